// Round 12
// baseline (209.444 us; speedup 1.0000x reference)
//
#include <hip/hip_runtime.h>
#include <hip/hip_bf16.h>

// B=4, S=2048, D=1024, H=16, DEPTH=64. Causal MHA, fp32 in/out, bf16 MFMA.

typedef __attribute__((ext_vector_type(8))) short bf16x8;
typedef __attribute__((ext_vector_type(4))) float f32x4;
typedef __attribute__((ext_vector_type(8))) unsigned short u16x8;

#define MFMA16(a, b, c) __builtin_amdgcn_mfma_f32_16x16x32_bf16(a, b, c, 0, 0, 0)

#define GLOAD_LDS16(gp, lp)                                                    \
  __builtin_amdgcn_global_load_lds(                                            \
      (const __attribute__((address_space(1))) void*)(gp),                     \
      (__attribute__((address_space(3))) void*)(lp), 16, 0, 0)

__device__ __forceinline__ unsigned short f2bf(float f) {
  union { float f; unsigned u; } x; x.f = f;
  unsigned u = x.u;
  return (unsigned short)((u + 0x7fffu + ((u >> 16) & 1u)) >> 16);
}

__device__ __forceinline__ unsigned pk2(float a, float b) {
  union { __hip_bfloat162 h; unsigned u; } cv;
  cv.h = __float22bfloat162_rn(float2{a, b});
  return cv.u;
}

// ---------------------------------------------------------------------------
// fp32 -> bf16 convert for q,k,v (3x8M) + weights (4x1M); packs qkv biases.
// ---------------------------------------------------------------------------
__global__ __launch_bounds__(256) void convert_kernel(
    const float* __restrict__ q, const float* __restrict__ k,
    const float* __restrict__ v, const float* __restrict__ wq,
    const float* __restrict__ wk, const float* __restrict__ wv,
    const float* __restrict__ wd, const float* __restrict__ bq,
    const float* __restrict__ bk, const float* __restrict__ bv,
    unsigned short* __restrict__ dst, float* __restrict__ bias_pack) {
  const size_t tid0 = (size_t)blockIdx.x * blockDim.x + threadIdx.x;
  const size_t nthreads = (size_t)gridDim.x * blockDim.x;
  if (tid0 < 3072) {
    bias_pack[tid0] = tid0 < 1024 ? bq[tid0]
                     : (tid0 < 2048 ? bk[tid0 - 1024] : bv[tid0 - 2048]);
  }
  const size_t NQ = 8192ull * 1024;
  const size_t NW = 1024ull * 1024;
  const size_t total_chunks = (3 * NQ + 4 * NW) / 8;
  for (size_t c = tid0; c < total_chunks; c += nthreads) {
    const size_t e = c * 8;
    const float* src;
    if (e < NQ) src = q + e;
    else if (e < 2 * NQ) src = k + (e - NQ);
    else if (e < 3 * NQ) src = v + (e - 2 * NQ);
    else {
      const size_t we = e - 3 * NQ;
      if (we < NW) src = wq + we;
      else if (we < 2 * NW) src = wk + (we - NW);
      else if (we < 3 * NW) src = wv + (we - 2 * NW);
      else src = wd + (we - 3 * NW);
    }
    f32x4 a = *(const f32x4*)(src);
    f32x4 b = *(const f32x4*)(src + 4);
    u16x8 o;
    o[0] = f2bf(a[0]); o[1] = f2bf(a[1]); o[2] = f2bf(a[2]); o[3] = f2bf(a[3]);
    o[4] = f2bf(b[0]); o[5] = f2bf(b[1]); o[6] = f2bf(b[2]); o[7] = f2bf(b[3]);
    *(u16x8*)(dst + e) = o;
  }
}

// ---------------------------------------------------------------------------
// Pipelined GEMM (R9 schedule, verified): C = A @ W^T + bias.
// BM=128, BN=256, BK=64, 512 threads = 8 waves, 3 LDS buffers, counted vmcnt.
// MODE 3: merged QKV — flat<512: z in {0,1} Q/K -> head layout;
//         flat>=512: V role-swapped -> V^T (B,H,64,S) pi-permuted.
// MODE 1: dense -> fp32 row-major.
// ---------------------------------------------------------------------------
template <int MODE>
__global__ __launch_bounds__(512, 2) void gemm8_kernel(
    const unsigned short* __restrict__ Abase,
    const unsigned short* __restrict__ Wbase,
    const float* __restrict__ biasbase, unsigned short* __restrict__ dstb,
    float* __restrict__ dstf) {
  __shared__ __attribute__((aligned(16))) unsigned short Ablk[3][128 * 64];
  __shared__ __attribute__((aligned(16))) unsigned short Bblk[3][256 * 64];
  const size_t NQ = 8192ull * 1024, NW = 1024ull * 1024;
  const int tot = (int)(gridDim.x * gridDim.y);
  int flat = (int)blockIdx.y * gridDim.x + blockIdx.x;
  flat = (flat & 7) * (tot >> 3) + (flat >> 3);

  const unsigned short* A;
  const unsigned short* W;
  int m0, n0, z;  // z: 0=Q,1=K,2=V (MODE 3); unused for MODE 1
  if (MODE == 3) {
    if (flat < 512) {
      z = flat >> 8;
      const int rem = flat & 255;
      m0 = (rem >> 2) * 128;   // 64 m-tiles
      n0 = (rem & 3) * 256;    // 4 n-tiles
      A = Abase + (size_t)z * NQ;
      W = Wbase + (size_t)z * NW;
    } else {
      z = 2;
      const int i = flat - 512;
      m0 = (i >> 5) * 128;     // 8 feature tiles
      n0 = (i & 31) * 256;     // 32 token tiles
      A = Wbase + 2 * NW;      // W_v
      W = Abase + 2 * NQ;      // v activations
    }
  } else {
    z = 0;
    m0 = (flat >> 2) * 128;
    n0 = (flat & 3) * 256;
    A = Abase;
    W = Wbase;
  }

  const int tid = threadIdx.x, lane = tid & 63, w = tid >> 6;
  const int wm = w >> 2, wn = w & 3;
  const int llo = lane & 15, lhi = lane >> 4;

  int srcA[2], srcB[4];
#pragma unroll
  for (int j = 0; j < 4; ++j) {
    const int c = tid + j * 512;
    const int off = (c >> 3) * 1024 + ((((c & 7) ^ ((c >> 3) & 7))) << 3);
    if (j < 2) srcA[j] = off;
    srcB[j] = off;
  }
  const unsigned short* Ag = A + (size_t)m0 * 1024;
  const unsigned short* Wg = W + (size_t)n0 * 1024;

#define STA(bi, kt_, j)                                                        \
  GLOAD_LDS16(Ag + srcA[j] + (kt_) * 64,                                       \
              (unsigned short*)Ablk[bi] + (tid + (j) * 512) * 8)
#define STB(bi, kt_, j)                                                        \
  GLOAD_LDS16(Wg + srcB[j] + (kt_) * 64,                                       \
              (unsigned short*)Bblk[bi] + (tid + (j) * 512) * 8)

  f32x4 acc[4][4] = {};
  const int cswz0 = ((lhi ^ (llo & 7)) << 3);
  const int cswz1 = (((4 + lhi) ^ (llo & 7)) << 3);

  STA(0, 0, 0); STA(0, 0, 1);
  STB(0, 0, 0); STB(0, 0, 1); STB(0, 0, 2); STB(0, 0, 3);
  STA(1, 1, 0); STA(1, 1, 1);
  STB(1, 1, 0); STB(1, 1, 1); STB(1, 1, 2); STB(1, 1, 3);

#pragma unroll
  for (int kt = 0; kt < 16; ++kt) {
    const int cb = kt % 3, nb = (kt + 2) % 3;
    __builtin_amdgcn_s_barrier();
    __builtin_amdgcn_sched_barrier(0);
    if (kt + 2 < 16) { STA(nb, kt + 2, 0); STA(nb, kt + 2, 1); STB(nb, kt + 2, 0); }
    if (kt <= 13) asm volatile("s_waitcnt vmcnt(9)" ::: "memory");
    else if (kt == 14) asm volatile("s_waitcnt vmcnt(6)" ::: "memory");
    else asm volatile("s_waitcnt vmcnt(0)" ::: "memory");
    __builtin_amdgcn_s_barrier();
    __builtin_amdgcn_sched_barrier(0);

    bf16x8 af[4][2], bf01[2][2];
#pragma unroll
    for (int mi = 0; mi < 4; ++mi) {
      const int ar = (wm * 64 + mi * 16 + llo) * 64;
      af[mi][0] = *(const bf16x8*)&Ablk[cb][ar + cswz0];
      af[mi][1] = *(const bf16x8*)&Ablk[cb][ar + cswz1];
    }
#pragma unroll
    for (int ni = 0; ni < 2; ++ni) {
      const int br = (wn * 64 + ni * 16 + llo) * 64;
      bf01[ni][0] = *(const bf16x8*)&Bblk[cb][br + cswz0];
      bf01[ni][1] = *(const bf16x8*)&Bblk[cb][br + cswz1];
    }
    __builtin_amdgcn_s_setprio(1);
#pragma unroll
    for (int mi = 0; mi < 4; ++mi)
#pragma unroll
      for (int ni = 0; ni < 2; ++ni) {
        acc[mi][ni] = MFMA16(af[mi][0], bf01[ni][0], acc[mi][ni]);
        acc[mi][ni] = MFMA16(af[mi][1], bf01[ni][1], acc[mi][ni]);
      }
    __builtin_amdgcn_s_setprio(0);
    __builtin_amdgcn_s_barrier();
    __builtin_amdgcn_sched_barrier(0);

    if (kt + 2 < 16) { STB(nb, kt + 2, 1); STB(nb, kt + 2, 2); STB(nb, kt + 2, 3); }
    bf16x8 bf23[2][2];
#pragma unroll
    for (int ni = 0; ni < 2; ++ni) {
      const int br = (wn * 64 + (ni + 2) * 16 + llo) * 64;
      bf23[ni][0] = *(const bf16x8*)&Bblk[cb][br + cswz0];
      bf23[ni][1] = *(const bf16x8*)&Bblk[cb][br + cswz1];
    }
    __builtin_amdgcn_s_setprio(1);
#pragma unroll
    for (int mi = 0; mi < 4; ++mi)
#pragma unroll
      for (int ni = 0; ni < 2; ++ni) {
        acc[mi][ni + 2] = MFMA16(af[mi][0], bf23[ni][0], acc[mi][ni + 2]);
        acc[mi][ni + 2] = MFMA16(af[mi][1], bf23[ni][1], acc[mi][ni + 2]);
      }
    __builtin_amdgcn_s_setprio(0);
  }
#undef STA
#undef STB

  const float osc = (MODE == 3 && z == 0) ? 0.1803368801f : 1.0f;
  const float* bias = (MODE == 3) ? biasbase + (size_t)z * 1024 : biasbase;
#pragma unroll
  for (int mi = 0; mi < 4; ++mi) {
#pragma unroll
    for (int ni = 0; ni < 4; ++ni) {
      const int n = n0 + wn * 64 + ni * 16 + llo;
      const int mbase = m0 + wm * 64 + mi * 16 + lhi * 4;
#pragma unroll
      for (int r = 0; r < 4; ++r) {
        const int m = mbase + r;
        if (MODE == 1) {
          dstf[(size_t)m * 1024 + n] = acc[mi][ni][r] + bias[n];
        } else if (z < 2) {
          const float val = (acc[mi][ni][r] + bias[n]) * osc;
          const int b = m >> 11, s = m & 2047, h = n >> 6, d = n & 63;
          dstb[(size_t)z * NQ + (((size_t)(b * 16 + h) * 2048 + s) * 64 + d)] =
              f2bf(val);
        } else {  // V: m = feature (h*64+d), n = token (b*2048+s)
          const float val = acc[mi][ni][r] + bias[m];
          const int h = m >> 6, d = m & 63, b = n >> 11, sidx = n & 2047;
          const int t = sidx & 63;
          const int ps = (sidx & ~63) | ((t & 15) << 2) | (t >> 4);  // pi(t)
          dstb[2 * NQ + (((size_t)(b * 16 + h) * 64 + d) * 2048 + ps)] =
              f2bf(val);
        }
      }
    }
  }
}

// ---------------------------------------------------------------------------
// Causal flash attention — R4 structure with SPLIT staging: V(t) flies during
// QK(t), K(t+1) flies during PV(t). Same single K/V buffers, same 2 barriers
// per tile (syncthreads drains vmcnt), but every drain now overlaps a compute
// phase instead of being fully exposed.
// Grid: (B*H, S/128). Block: 256 = 4 waves, wave owns 32 q-rows. KV tile 64.
// No online max (Q pre-scaled to log2 domain). l via ones-column MFMA
// (Vt row 64 = 1.0). P stored k-pi-permuted, packed ds_write_b64.
// ---------------------------------------------------------------------------
__global__ __launch_bounds__(256, 4) void attn_kernel(
    const unsigned short* __restrict__ Qp, const unsigned short* __restrict__ Kp,
    const unsigned short* __restrict__ Vtp, unsigned short* __restrict__ attn_out) {
  __shared__ __attribute__((aligned(16))) unsigned short Klds[64 * 64];  // [kv][d] swz
  __shared__ __attribute__((aligned(16))) unsigned short Vt[80 * 64];    // [d][pi(kv)] swz
  __shared__ __attribute__((aligned(16))) unsigned short Plds[4 * 32 * 72];
  const int bh = blockIdx.x;
  const int qt = 15 - blockIdx.y;  // biggest q-tiles dispatch first
  const int tid = threadIdx.x, lane = tid & 63, w = tid >> 6;
  const int llo = lane & 15, lhi = lane >> 4;
  const int q0 = qt * 128;
  const int qbase = q0 + w * 32;

  // init Vt rows 64..79: row 64 = 1.0 (l-column), rows 65..79 = 0
  {
    const unsigned v16 = (tid < 16) ? 0x3F80u : 0u;
    const unsigned vv = v16 | (v16 << 16);
    *(uint2*)&Vt[64 * 64 + tid * 4] = make_uint2(vv, vv);
  }

  // Q fragments (pre-scaled): rows qbase+mi*16+llo, k-halves
  bf16x8 qf[2][2];
#pragma unroll
  for (int mi = 0; mi < 2; ++mi) {
    const unsigned short* qptr =
        Qp + ((size_t)bh * 2048 + qbase + mi * 16 + llo) * 64 + lhi * 8;
    qf[mi][0] = *(const bf16x8*)qptr;
    qf[mi][1] = *(const bf16x8*)(qptr + 32);
  }

  f32x4 o[2][5] = {};  // [mi][dblk]; dblk 4 = l column

  const size_t kbase = (size_t)bh * (64 * 2048);
  const int r0 = tid >> 3, r1 = r0 + 32;
  const int scb = (tid & 7) * 16;
  const int kcol0 = (scb ^ ((r0 & 7) << 4)) >> 1;
  const int kcol1 = (scb ^ ((r1 & 7) << 4)) >> 1;
  const int koff0 = r0 * 64 + kcol0, koff1 = r1 * 64 + kcol1;
  const int voff0 = r0 * 2048 + kcol0, voff1 = r1 * 2048 + kcol1;
  unsigned short* pw = &Plds[w * (32 * 72)];

#define STAGE_K(kv0_)                                                          \
  do {                                                                         \
    GLOAD_LDS16(Kp + kbase + (size_t)(kv0_)*64 + koff0, &Klds[tid * 8]);       \
    GLOAD_LDS16(Kp + kbase + (size_t)(kv0_)*64 + koff1, &Klds[2048 + tid * 8]);\
  } while (0)
#define STAGE_V(kv0_)                                                          \
  do {                                                                         \
    GLOAD_LDS16(Vtp + kbase + (kv0_) + voff0, &Vt[tid * 8]);                   \
    GLOAD_LDS16(Vtp + kbase + (kv0_) + voff1, &Vt[2048 + tid * 8]);            \
  } while (0)

  const int nkt = 2 * (qt + 1);
  STAGE_K(0);
  STAGE_V(0);
  __syncthreads();

  for (int kt = 0; kt < nkt; ++kt) {
    const int kv0 = kt * 64;
    const bool act = (kv0 <= qbase + 31);  // wave-uniform causal activity

    // ---- phase 1: QK^T (reads Klds); V(t) already landed (prev drain)
    f32x4 s[2][4];
    if (act) {
#pragma unroll
      for (int j = 0; j < 2; ++j)
#pragma unroll
        for (int b4 = 0; b4 < 4; ++b4) s[j][b4] = f32x4{0.f, 0.f, 0.f, 0.f};
#pragma unroll
      for (int b4 = 0; b4 < 4; ++b4) {
        const int row = b4 * 16 + llo;
        const int sw = (row & 7) << 3;
        const bf16x8 k0 = *(const bf16x8*)&Klds[row * 64 + ((lhi * 8) ^ sw)];
        const bf16x8 k1 = *(const bf16x8*)&Klds[row * 64 + ((32 + lhi * 8) ^ sw)];
        s[0][b4] = MFMA16(qf[0][0], k0, s[0][b4]);
        s[0][b4] = MFMA16(qf[0][1], k1, s[0][b4]);
        s[1][b4] = MFMA16(qf[1][0], k0, s[1][b4]);
        s[1][b4] = MFMA16(qf[1][1], k1, s[1][b4]);
      }

      // P = exp2(S) (+causal mask), packed pi-permuted store (wave-local)
      const bool needm = (kv0 + 63 > qbase);
#pragma unroll
      for (int mi = 0; mi < 2; ++mi) {
#pragma unroll
        for (int r = 0; r < 4; ++r) {
          float sv0 = s[mi][0][r], sv1 = s[mi][1][r];
          float sv2 = s[mi][2][r], sv3 = s[mi][3][r];
          if (needm) {
            const int qrow = qbase + mi * 16 + lhi * 4 + r;
            if (kv0 + llo > qrow) sv0 = -1e9f;
            if (kv0 + 16 + llo > qrow) sv1 = -1e9f;
            if (kv0 + 32 + llo > qrow) sv2 = -1e9f;
            if (kv0 + 48 + llo > qrow) sv3 = -1e9f;
          }
          const float p0 = exp2f(sv0), p1 = exp2f(sv1);
          const float p2 = exp2f(sv2), p3 = exp2f(sv3);
          const int prow = mi * 16 + lhi * 4 + r;
          *(uint2*)&pw[prow * 72 + llo * 4] =
              make_uint2(pk2(p0, p1), pk2(p2, p3));
        }
      }
    }

    __syncthreads();  // K-buf free (QK done all waves); drains V(t) (landed)

    // ---- phase 2: issue K(t+1) (flies during PV), then PV (reads Vt)
    if (kt + 1 < nkt) STAGE_K(kv0 + 64);
    if (act) {
      bf16x8 pa[2][2];
#pragma unroll
      for (int mi = 0; mi < 2; ++mi) {
        pa[mi][0] = *(const bf16x8*)&pw[(mi * 16 + llo) * 72 + lhi * 8];
        pa[mi][1] = *(const bf16x8*)&pw[(mi * 16 + llo) * 72 + 32 + lhi * 8];
      }
#pragma unroll
      for (int dblk = 0; dblk < 5; ++dblk) {
        const int row = dblk * 16 + llo;
        const int sw = (row & 7) << 3;
        const bf16x8 v0 = *(const bf16x8*)&Vt[row * 64 + ((lhi * 8) ^ sw)];
        const bf16x8 v1 = *(const bf16x8*)&Vt[row * 64 + ((32 + lhi * 8) ^ sw)];
        o[0][dblk] = MFMA16(pa[0][0], v0, o[0][dblk]);
        o[0][dblk] = MFMA16(pa[0][1], v1, o[0][dblk]);
        o[1][dblk] = MFMA16(pa[1][0], v0, o[1][dblk]);
        o[1][dblk] = MFMA16(pa[1][1], v1, o[1][dblk]);
      }
    }

    __syncthreads();  // V-buf free (PV done all waves); drains K(t+1)

    // ---- issue V(t+1): flies during QK(t+1), drained at its first barrier
    if (kt + 1 < nkt) STAGE_V(kv0 + 64);
  }
#undef STAGE_K
#undef STAGE_V

  // ---- epilogue: O/l, scatter to (B,S,D) bf16. l lives in lanes llo==0.
  const int b = bh >> 4, h = bh & 15;
#pragma unroll
  for (int mi = 0; mi < 2; ++mi) {
#pragma unroll
    for (int r = 0; r < 4; ++r) {
      const float lsum = __shfl(o[mi][4][r], lane & 48);
      const float inv = 1.0f / lsum;
      const int qrow = qbase + mi * 16 + lhi * 4 + r;
      const size_t base = ((size_t)b * 2048 + qrow) * 1024 + h * 64;
#pragma unroll
      for (int dblk = 0; dblk < 4; ++dblk)
        attn_out[base + dblk * 16 + llo] = f2bf(o[mi][dblk][r] * inv);
    }
  }
}

// ---------------------------------------------------------------------------
extern "C" void kernel_launch(void* const* d_in, const int* in_sizes, int n_in,
                              void* d_out, int out_size, void* d_ws,
                              size_t ws_size, hipStream_t stream) {
  const float* q = (const float*)d_in[0];
  const float* k = (const float*)d_in[1];
  const float* v = (const float*)d_in[2];
  const float* wq_w = (const float*)d_in[3];
  const float* wq_b = (const float*)d_in[4];
  const float* wk_w = (const float*)d_in[5];
  const float* wk_b = (const float*)d_in[6];
  const float* wv_w = (const float*)d_in[7];
  const float* wv_b = (const float*)d_in[8];
  const float* dense_w = (const float*)d_in[9];
  const float* dense_b = (const float*)d_in[10];
  float* out = (float*)d_out;

  char* ws = (char*)d_ws;
  const size_t MB = 1024ull * 1024;
  unsigned short* qkv_bf = (unsigned short*)(ws);
  unsigned short* w_bf = (unsigned short*)(ws + 48 * MB);
  float* bias_pack = (float*)(ws + 56 * MB);
  unsigned short* qkvp = (unsigned short*)(ws + 57 * MB);
  unsigned short* attn_o = (unsigned short*)(ws + 105 * MB);
  const size_t PEL = 8192ull * 1024;

  convert_kernel<<<dim3(2048), dim3(256), 0, stream>>>(
      q, k, v, wq_w, wk_w, wv_w, dense_w, wq_b, wk_b, wv_b, qkv_bf, bias_pack);

  // Merged Q (scaled) + K -> (B,H,S,64) and V^T -> (B,H,64,S): 768 blocks
  gemm8_kernel<3><<<dim3(768), dim3(512), 0, stream>>>(
      qkv_bf, w_bf, bias_pack, qkvp, nullptr);

  attn_kernel<<<dim3(64, 16), dim3(256), 0, stream>>>(
      qkvp, qkvp + PEL, qkvp + 2 * PEL, attn_o);

  // dense: 256 blocks = 1 round
  gemm8_kernel<1><<<dim3(4, 64), dim3(512), 0, stream>>>(
      attn_o, w_bf + 3ull * 1024 * 1024, dense_b, nullptr, out);
}

// Round 13
// 186.849 us; speedup vs baseline: 1.1209x; 1.1209x over previous
//
#include <hip/hip_runtime.h>
#include <hip/hip_bf16.h>

// B=4, S=2048, D=1024, H=16, DEPTH=64. Causal MHA, fp32 in/out, bf16 MFMA.

typedef __attribute__((ext_vector_type(8))) short bf16x8;
typedef __attribute__((ext_vector_type(4))) float f32x4;
typedef __attribute__((ext_vector_type(8))) unsigned short u16x8;

#define MFMA16(a, b, c) __builtin_amdgcn_mfma_f32_16x16x32_bf16(a, b, c, 0, 0, 0)

#define GLOAD_LDS16(gp, lp)                                                    \
  __builtin_amdgcn_global_load_lds(                                            \
      (const __attribute__((address_space(1))) void*)(gp),                     \
      (__attribute__((address_space(3))) void*)(lp), 16, 0, 0)

__device__ __forceinline__ unsigned short f2bf(float f) {
  union { float f; unsigned u; } x; x.f = f;
  unsigned u = x.u;
  return (unsigned short)((u + 0x7fffu + ((u >> 16) & 1u)) >> 16);
}

__device__ __forceinline__ unsigned pk2(float a, float b) {
  union { __hip_bfloat162 h; unsigned u; } cv;
  cv.h = __float22bfloat162_rn(float2{a, b});
  return cv.u;
}

// ---------------------------------------------------------------------------
// fp32 -> bf16 convert for q,k,v (3x8M) + weights (4x1M); packs qkv biases.
// ---------------------------------------------------------------------------
__global__ __launch_bounds__(256) void convert_kernel(
    const float* __restrict__ q, const float* __restrict__ k,
    const float* __restrict__ v, const float* __restrict__ wq,
    const float* __restrict__ wk, const float* __restrict__ wv,
    const float* __restrict__ wd, const float* __restrict__ bq,
    const float* __restrict__ bk, const float* __restrict__ bv,
    unsigned short* __restrict__ dst, float* __restrict__ bias_pack) {
  const size_t tid0 = (size_t)blockIdx.x * blockDim.x + threadIdx.x;
  const size_t nthreads = (size_t)gridDim.x * blockDim.x;
  if (tid0 < 3072) {
    bias_pack[tid0] = tid0 < 1024 ? bq[tid0]
                     : (tid0 < 2048 ? bk[tid0 - 1024] : bv[tid0 - 2048]);
  }
  const size_t NQ = 8192ull * 1024;
  const size_t NW = 1024ull * 1024;
  const size_t total_chunks = (3 * NQ + 4 * NW) / 8;
  for (size_t c = tid0; c < total_chunks; c += nthreads) {
    const size_t e = c * 8;
    const float* src;
    if (e < NQ) src = q + e;
    else if (e < 2 * NQ) src = k + (e - NQ);
    else if (e < 3 * NQ) src = v + (e - 2 * NQ);
    else {
      const size_t we = e - 3 * NQ;
      if (we < NW) src = wq + we;
      else if (we < 2 * NW) src = wk + (we - NW);
      else if (we < 3 * NW) src = wv + (we - 2 * NW);
      else src = wd + (we - 3 * NW);
    }
    f32x4 a = *(const f32x4*)(src);
    f32x4 b = *(const f32x4*)(src + 4);
    u16x8 o;
    o[0] = f2bf(a[0]); o[1] = f2bf(a[1]); o[2] = f2bf(a[2]); o[3] = f2bf(a[3]);
    o[4] = f2bf(b[0]); o[5] = f2bf(b[1]); o[6] = f2bf(b[2]); o[7] = f2bf(b[3]);
    *(u16x8*)(dst + e) = o;
  }
}

// ---------------------------------------------------------------------------
// Pipelined GEMM (R9/R11 schedule, verified): C = A @ W^T + bias.
// BM=128, BN=256, BK=64, 512 threads = 8 waves, 3 LDS buffers, counted vmcnt.
// MODE 0 (z=0,1): Q (log2-scaled) / K -> head layout (B,H,S,64).
// MODE 2: V role-swapped (A=W_v, W=v-act) -> V^T (B,H,64,S) pi-permuted.
// MODE 1: dense -> fp32 row-major.
// ---------------------------------------------------------------------------
template <int MODE>
__global__ __launch_bounds__(512, 2) void gemm8_kernel(
    const unsigned short* __restrict__ Abase,
    const unsigned short* __restrict__ Wbase,
    const float* __restrict__ biasbase, unsigned short* __restrict__ dstb,
    float* __restrict__ dstf) {
  __shared__ __attribute__((aligned(16))) unsigned short Ablk[3][128 * 64];
  __shared__ __attribute__((aligned(16))) unsigned short Bblk[3][256 * 64];
  const size_t NQ = 8192ull * 1024, NW = 1024ull * 1024;
  const int nx = gridDim.x, ny = gridDim.y;
  const int tot = nx * ny * (int)gridDim.z;
  int flat = ((int)blockIdx.z * ny + blockIdx.y) * nx + blockIdx.x;
  flat = (flat & 7) * (tot >> 3) + (flat >> 3);
  const int bx = flat % nx;
  const int tmp = flat / nx;
  const int by = tmp % ny;
  const int z = tmp / ny;

  const unsigned short* A;
  const unsigned short* W;
  if (MODE == 0) { A = Abase + (size_t)z * NQ; W = Wbase + (size_t)z * NW; }
  else if (MODE == 2) { A = Wbase + 2 * NW; W = Abase + 2 * NQ; }
  else { A = Abase; W = Wbase; }
  const int m0 = by * 128, n0 = bx * 256;

  const int tid = threadIdx.x, lane = tid & 63, w = tid >> 6;
  const int wm = w >> 2, wn = w & 3;
  const int llo = lane & 15, lhi = lane >> 4;

  int srcA[2], srcB[4];
#pragma unroll
  for (int j = 0; j < 4; ++j) {
    const int c = tid + j * 512;
    const int off = (c >> 3) * 1024 + ((((c & 7) ^ ((c >> 3) & 7))) << 3);
    if (j < 2) srcA[j] = off;
    srcB[j] = off;
  }
  const unsigned short* Ag = A + (size_t)m0 * 1024;
  const unsigned short* Wg = W + (size_t)n0 * 1024;

#define STA(bi, kt_, j)                                                        \
  GLOAD_LDS16(Ag + srcA[j] + (kt_) * 64,                                       \
              (unsigned short*)Ablk[bi] + (tid + (j) * 512) * 8)
#define STB(bi, kt_, j)                                                        \
  GLOAD_LDS16(Wg + srcB[j] + (kt_) * 64,                                       \
              (unsigned short*)Bblk[bi] + (tid + (j) * 512) * 8)

  f32x4 acc[4][4] = {};
  const int cswz0 = ((lhi ^ (llo & 7)) << 3);
  const int cswz1 = (((4 + lhi) ^ (llo & 7)) << 3);

  STA(0, 0, 0); STA(0, 0, 1);
  STB(0, 0, 0); STB(0, 0, 1); STB(0, 0, 2); STB(0, 0, 3);
  STA(1, 1, 0); STA(1, 1, 1);
  STB(1, 1, 0); STB(1, 1, 1); STB(1, 1, 2); STB(1, 1, 3);

#pragma unroll
  for (int kt = 0; kt < 16; ++kt) {
    const int cb = kt % 3, nb = (kt + 2) % 3;
    __builtin_amdgcn_s_barrier();
    __builtin_amdgcn_sched_barrier(0);
    if (kt + 2 < 16) { STA(nb, kt + 2, 0); STA(nb, kt + 2, 1); STB(nb, kt + 2, 0); }
    if (kt <= 13) asm volatile("s_waitcnt vmcnt(9)" ::: "memory");
    else if (kt == 14) asm volatile("s_waitcnt vmcnt(6)" ::: "memory");
    else asm volatile("s_waitcnt vmcnt(0)" ::: "memory");
    __builtin_amdgcn_s_barrier();
    __builtin_amdgcn_sched_barrier(0);

    bf16x8 af[4][2], bf01[2][2];
#pragma unroll
    for (int mi = 0; mi < 4; ++mi) {
      const int ar = (wm * 64 + mi * 16 + llo) * 64;
      af[mi][0] = *(const bf16x8*)&Ablk[cb][ar + cswz0];
      af[mi][1] = *(const bf16x8*)&Ablk[cb][ar + cswz1];
    }
#pragma unroll
    for (int ni = 0; ni < 2; ++ni) {
      const int br = (wn * 64 + ni * 16 + llo) * 64;
      bf01[ni][0] = *(const bf16x8*)&Bblk[cb][br + cswz0];
      bf01[ni][1] = *(const bf16x8*)&Bblk[cb][br + cswz1];
    }
    __builtin_amdgcn_s_setprio(1);
#pragma unroll
    for (int mi = 0; mi < 4; ++mi)
#pragma unroll
      for (int ni = 0; ni < 2; ++ni) {
        acc[mi][ni] = MFMA16(af[mi][0], bf01[ni][0], acc[mi][ni]);
        acc[mi][ni] = MFMA16(af[mi][1], bf01[ni][1], acc[mi][ni]);
      }
    __builtin_amdgcn_s_setprio(0);
    __builtin_amdgcn_s_barrier();
    __builtin_amdgcn_sched_barrier(0);

    if (kt + 2 < 16) { STB(nb, kt + 2, 1); STB(nb, kt + 2, 2); STB(nb, kt + 2, 3); }
    bf16x8 bf23[2][2];
#pragma unroll
    for (int ni = 0; ni < 2; ++ni) {
      const int br = (wn * 64 + (ni + 2) * 16 + llo) * 64;
      bf23[ni][0] = *(const bf16x8*)&Bblk[cb][br + cswz0];
      bf23[ni][1] = *(const bf16x8*)&Bblk[cb][br + cswz1];
    }
    __builtin_amdgcn_s_setprio(1);
#pragma unroll
    for (int mi = 0; mi < 4; ++mi)
#pragma unroll
      for (int ni = 0; ni < 2; ++ni) {
        acc[mi][ni + 2] = MFMA16(af[mi][0], bf23[ni][0], acc[mi][ni + 2]);
        acc[mi][ni + 2] = MFMA16(af[mi][1], bf23[ni][1], acc[mi][ni + 2]);
      }
    __builtin_amdgcn_s_setprio(0);
  }
#undef STA
#undef STB

  const float osc = (MODE == 0 && z == 0) ? 0.1803368801f : 1.0f;
  const float* bias = (MODE == 0) ? biasbase + (size_t)z * 1024
                     : (MODE == 2) ? biasbase + 2048 : biasbase;
#pragma unroll
  for (int mi = 0; mi < 4; ++mi) {
#pragma unroll
    for (int ni = 0; ni < 4; ++ni) {
      const int n = n0 + wn * 64 + ni * 16 + llo;
      const int mbase = m0 + wm * 64 + mi * 16 + lhi * 4;
#pragma unroll
      for (int r = 0; r < 4; ++r) {
        const int m = mbase + r;
        if (MODE == 1) {
          dstf[(size_t)m * 1024 + n] = acc[mi][ni][r] + bias[n];
        } else if (MODE == 0) {
          const float val = (acc[mi][ni][r] + bias[n]) * osc;
          const int b = m >> 11, s = m & 2047, h = n >> 6, d = n & 63;
          dstb[(size_t)z * NQ + (((size_t)(b * 16 + h) * 2048 + s) * 64 + d)] =
              f2bf(val);
        } else {
          const float val = acc[mi][ni][r] + bias[m];
          const int h = m >> 6, d = m & 63, b = n >> 11, sidx = n & 2047;
          const int t = sidx & 63;
          const int ps = (sidx & ~63) | ((t & 15) << 2) | (t >> 4);  // pi(t)
          dstb[2 * NQ + (((size_t)(b * 16 + h) * 64 + d) * 2048 + ps)] =
              f2bf(val);
        }
      }
    }
  }
}

// ---------------------------------------------------------------------------
// Causal flash attention — split staging (R12, verified ~61us): V(t) flies
// during QK(t), K(t+1) flies during PV(t). Single K/V buffers, 2 barriers per
// tile; every vmcnt drain overlaps a compute phase.
// Grid: (B*H, S/128). Block: 256 = 4 waves, wave owns 32 q-rows. KV tile 64.
// No online max (Q pre-scaled to log2 domain). l via ones-column MFMA
// (Vt row 64 = 1.0). P stored k-pi-permuted, packed ds_write_b64.
// ---------------------------------------------------------------------------
__global__ __launch_bounds__(256, 4) void attn_kernel(
    const unsigned short* __restrict__ Qp, const unsigned short* __restrict__ Kp,
    const unsigned short* __restrict__ Vtp, unsigned short* __restrict__ attn_out) {
  __shared__ __attribute__((aligned(16))) unsigned short Klds[64 * 64];  // [kv][d] swz
  __shared__ __attribute__((aligned(16))) unsigned short Vt[80 * 64];    // [d][pi(kv)] swz
  __shared__ __attribute__((aligned(16))) unsigned short Plds[4 * 32 * 72];
  const int bh = blockIdx.x;
  const int qt = 15 - blockIdx.y;  // biggest q-tiles dispatch first
  const int tid = threadIdx.x, lane = tid & 63, w = tid >> 6;
  const int llo = lane & 15, lhi = lane >> 4;
  const int q0 = qt * 128;
  const int qbase = q0 + w * 32;

  // init Vt rows 64..79: row 64 = 1.0 (l-column), rows 65..79 = 0
  {
    const unsigned v16 = (tid < 16) ? 0x3F80u : 0u;
    const unsigned vv = v16 | (v16 << 16);
    *(uint2*)&Vt[64 * 64 + tid * 4] = make_uint2(vv, vv);
  }

  // Q fragments (pre-scaled): rows qbase+mi*16+llo, k-halves
  bf16x8 qf[2][2];
#pragma unroll
  for (int mi = 0; mi < 2; ++mi) {
    const unsigned short* qptr =
        Qp + ((size_t)bh * 2048 + qbase + mi * 16 + llo) * 64 + lhi * 8;
    qf[mi][0] = *(const bf16x8*)qptr;
    qf[mi][1] = *(const bf16x8*)(qptr + 32);
  }

  f32x4 o[2][5] = {};  // [mi][dblk]; dblk 4 = l column

  const size_t kbase = (size_t)bh * (64 * 2048);
  const int r0 = tid >> 3, r1 = r0 + 32;
  const int scb = (tid & 7) * 16;
  const int kcol0 = (scb ^ ((r0 & 7) << 4)) >> 1;
  const int kcol1 = (scb ^ ((r1 & 7) << 4)) >> 1;
  const int koff0 = r0 * 64 + kcol0, koff1 = r1 * 64 + kcol1;
  const int voff0 = r0 * 2048 + kcol0, voff1 = r1 * 2048 + kcol1;
  unsigned short* pw = &Plds[w * (32 * 72)];

#define STAGE_K(kv0_)                                                          \
  do {                                                                         \
    GLOAD_LDS16(Kp + kbase + (size_t)(kv0_)*64 + koff0, &Klds[tid * 8]);       \
    GLOAD_LDS16(Kp + kbase + (size_t)(kv0_)*64 + koff1, &Klds[2048 + tid * 8]);\
  } while (0)
#define STAGE_V(kv0_)                                                          \
  do {                                                                         \
    GLOAD_LDS16(Vtp + kbase + (kv0_) + voff0, &Vt[tid * 8]);                   \
    GLOAD_LDS16(Vtp + kbase + (kv0_) + voff1, &Vt[2048 + tid * 8]);            \
  } while (0)

  const int nkt = 2 * (qt + 1);
  STAGE_K(0);
  STAGE_V(0);
  __syncthreads();

  for (int kt = 0; kt < nkt; ++kt) {
    const int kv0 = kt * 64;
    const bool act = (kv0 <= qbase + 31);  // wave-uniform causal activity

    // ---- phase 1: QK^T (reads Klds); V(t) already landed (prev drain)
    f32x4 s[2][4];
    if (act) {
#pragma unroll
      for (int j = 0; j < 2; ++j)
#pragma unroll
        for (int b4 = 0; b4 < 4; ++b4) s[j][b4] = f32x4{0.f, 0.f, 0.f, 0.f};
#pragma unroll
      for (int b4 = 0; b4 < 4; ++b4) {
        const int row = b4 * 16 + llo;
        const int sw = (row & 7) << 3;
        const bf16x8 k0 = *(const bf16x8*)&Klds[row * 64 + ((lhi * 8) ^ sw)];
        const bf16x8 k1 = *(const bf16x8*)&Klds[row * 64 + ((32 + lhi * 8) ^ sw)];
        s[0][b4] = MFMA16(qf[0][0], k0, s[0][b4]);
        s[0][b4] = MFMA16(qf[0][1], k1, s[0][b4]);
        s[1][b4] = MFMA16(qf[1][0], k0, s[1][b4]);
        s[1][b4] = MFMA16(qf[1][1], k1, s[1][b4]);
      }

      // P = exp2(S) (+causal mask), packed pi-permuted store (wave-local)
      const bool needm = (kv0 + 63 > qbase);
#pragma unroll
      for (int mi = 0; mi < 2; ++mi) {
#pragma unroll
        for (int r = 0; r < 4; ++r) {
          float sv0 = s[mi][0][r], sv1 = s[mi][1][r];
          float sv2 = s[mi][2][r], sv3 = s[mi][3][r];
          if (needm) {
            const int qrow = qbase + mi * 16 + lhi * 4 + r;
            if (kv0 + llo > qrow) sv0 = -1e9f;
            if (kv0 + 16 + llo > qrow) sv1 = -1e9f;
            if (kv0 + 32 + llo > qrow) sv2 = -1e9f;
            if (kv0 + 48 + llo > qrow) sv3 = -1e9f;
          }
          const float p0 = exp2f(sv0), p1 = exp2f(sv1);
          const float p2 = exp2f(sv2), p3 = exp2f(sv3);
          const int prow = mi * 16 + lhi * 4 + r;
          *(uint2*)&pw[prow * 72 + llo * 4] =
              make_uint2(pk2(p0, p1), pk2(p2, p3));
        }
      }
    }

    __syncthreads();  // K-buf free (QK done all waves); drains V(t) (landed)

    // ---- phase 2: issue K(t+1) (flies during PV), then PV (reads Vt)
    if (kt + 1 < nkt) STAGE_K(kv0 + 64);
    if (act) {
      bf16x8 pa[2][2];
#pragma unroll
      for (int mi = 0; mi < 2; ++mi) {
        pa[mi][0] = *(const bf16x8*)&pw[(mi * 16 + llo) * 72 + lhi * 8];
        pa[mi][1] = *(const bf16x8*)&pw[(mi * 16 + llo) * 72 + 32 + lhi * 8];
      }
#pragma unroll
      for (int dblk = 0; dblk < 5; ++dblk) {
        const int row = dblk * 16 + llo;
        const int sw = (row & 7) << 3;
        const bf16x8 v0 = *(const bf16x8*)&Vt[row * 64 + ((lhi * 8) ^ sw)];
        const bf16x8 v1 = *(const bf16x8*)&Vt[row * 64 + ((32 + lhi * 8) ^ sw)];
        o[0][dblk] = MFMA16(pa[0][0], v0, o[0][dblk]);
        o[0][dblk] = MFMA16(pa[0][1], v1, o[0][dblk]);
        o[1][dblk] = MFMA16(pa[1][0], v0, o[1][dblk]);
        o[1][dblk] = MFMA16(pa[1][1], v1, o[1][dblk]);
      }
    }

    __syncthreads();  // V-buf free (PV done all waves); drains K(t+1)

    // ---- issue V(t+1): flies during QK(t+1), drained at its first barrier
    if (kt + 1 < nkt) STAGE_V(kv0 + 64);
  }
#undef STAGE_K
#undef STAGE_V

  // ---- epilogue: O/l, scatter to (B,S,D) bf16. l lives in lanes llo==0.
  const int b = bh >> 4, h = bh & 15;
#pragma unroll
  for (int mi = 0; mi < 2; ++mi) {
#pragma unroll
    for (int r = 0; r < 4; ++r) {
      const float lsum = __shfl(o[mi][4][r], lane & 48);
      const float inv = 1.0f / lsum;
      const int qrow = qbase + mi * 16 + lhi * 4 + r;
      const size_t base = ((size_t)b * 2048 + qrow) * 1024 + h * 64;
#pragma unroll
      for (int dblk = 0; dblk < 4; ++dblk)
        attn_out[base + dblk * 16 + llo] = f2bf(o[mi][dblk][r] * inv);
    }
  }
}

// ---------------------------------------------------------------------------
extern "C" void kernel_launch(void* const* d_in, const int* in_sizes, int n_in,
                              void* d_out, int out_size, void* d_ws,
                              size_t ws_size, hipStream_t stream) {
  const float* q = (const float*)d_in[0];
  const float* k = (const float*)d_in[1];
  const float* v = (const float*)d_in[2];
  const float* wq_w = (const float*)d_in[3];
  const float* wq_b = (const float*)d_in[4];
  const float* wk_w = (const float*)d_in[5];
  const float* wk_b = (const float*)d_in[6];
  const float* wv_w = (const float*)d_in[7];
  const float* wv_b = (const float*)d_in[8];
  const float* dense_w = (const float*)d_in[9];
  const float* dense_b = (const float*)d_in[10];
  float* out = (float*)d_out;

  char* ws = (char*)d_ws;
  const size_t MB = 1024ull * 1024;
  unsigned short* qkv_bf = (unsigned short*)(ws);
  unsigned short* w_bf = (unsigned short*)(ws + 48 * MB);
  float* bias_pack = (float*)(ws + 56 * MB);
  unsigned short* qkvp = (unsigned short*)(ws + 57 * MB);
  unsigned short* attn_o = (unsigned short*)(ws + 105 * MB);
  const size_t PEL = 8192ull * 1024;

  convert_kernel<<<dim3(2048), dim3(256), 0, stream>>>(
      q, k, v, wq_w, wk_w, wv_w, dense_w, wq_b, wk_b, wv_b, qkv_bf, bias_pack);

  // Q (scaled), K -> (B,H,S,64): 512 blocks = 2 exact CU-rounds
  gemm8_kernel<0><<<dim3(4, 64, 2), dim3(512), 0, stream>>>(
      qkv_bf, w_bf, bias_pack, qkvp, nullptr);

  // V role-swapped -> V^T (B,H,64,S) pi-permuted: 256 blocks = 1 round
  gemm8_kernel<2><<<dim3(32, 8, 1), dim3(512), 0, stream>>>(
      qkv_bf, w_bf, bias_pack, qkvp, nullptr);

  attn_kernel<<<dim3(64, 16), dim3(256), 0, stream>>>(
      qkvp, qkvp + PEL, qkvp + 2 * PEL, attn_o);

  // dense: 256 blocks = 1 round
  gemm8_kernel<1><<<dim3(4, 64), dim3(512), 0, stream>>>(
      attn_o, w_bf + 3ull * 1024 * 1024, dense_b, nullptr, out);
}